// Round 13
// baseline (2938.532 us; speedup 1.0000x reference)
//
#include <hip/hip_runtime.h>

// ConvLSTM fp32, round 13: r10 revert + occupancy play. conv xs is now a
// single-buffered flat [64][142] tile (36.4KB -> 4 blocks/CU, was 71.7KB/2),
// ci-stride 142 fixes the 8-way staging-scatter conflict (4*142%32=24 ->
// 4 banks vs 2). One extra barrier per du, absorbed by 4x TLP. Inner loop
// byte-identical to r10 (VGPR 108, no scratch). No register pipelining:
// r7/r11/r12 all proved the compiler spills it.

#define WSTRIDE 442368   // per-layer conv weight elements: 27*64*256
#define XS      32768    // one k-slab of h: 512*64
#define HSTRIDE 229376   // nc stride of h: 7*512*64

__device__ __forceinline__ float wred_sum(float v) {
    #pragma unroll
    for (int o = 32; o > 0; o >>= 1) v += __shfl_down(v, o, 64);
    return __shfl(v, 0, 64);
}
__device__ __forceinline__ float fsig(float x)  { return 1.f / (1.f + __expf(-x)); }
__device__ __forceinline__ float ftanh(float x) { return 1.f - 2.f / (__expf(2.f*x) + 1.f); }

struct CJob { const float* x; const float* wt; const float* bias; float* y; };
struct GJob {
    const float* giraw; const float* ghat;
    const float* ginw; const float* ginb;
    const float* ghw;  const float* ghb;
    float* cx; float* h; int k; int k0;
};

// h[nc][s][vox][ch] = emb[tok][ch]
__global__ __launch_bounds__(256) void embed_kernel(
    const int* __restrict__ code, const int* __restrict__ ncode,
    const float* __restrict__ emb, float* __restrict__ h)
{
    int e = blockIdx.x * 256 + threadIdx.x;   // < 2*7*512*64 = 458752
    int ch = e & 63;
    int pos = e >> 6;            // nc*7*512 + s*512 + vox
    int vox = pos & 511;
    int t = pos >> 9;            // nc*7 + s
    int s = t % 7, nc = t / 7;
    int tok = (s < 5) ? code[(nc*5 + s)*512 + vox]
                      : ncode[(nc*3 + (s-5))*512 + vox];
    h[e] = emb[tok*64 + ch];
}

// One 3x3x3 SAME conv job (Cin=64 -> Cout=256) over 2 slabs; up to 4 jobs
// per launch via blockIdx.y. Block = full u-plane (64 vox) x 16 co,
// thread = 4co x 4vox (2x2 patch), K(ci) split 4-way + LDS reduce.
// grid.x per job = 2 slab * 8 u * 16 cg = 256.
__global__ __launch_bounds__(256, 4) void conv_step_kernel(CJob j0, CJob j1, CJob j2, CJob j3)
{
    CJob J = j0;
    if (blockIdx.y == 1) J = j1;
    else if (blockIdx.y == 2) J = j2;
    else if (blockIdx.y == 3) J = j3;

    // flat halo-padded du-slab tile: row stride 14 (10 rows used), ci stride
    // 142 (even -> b64-aligned reads; 4*142 % 32 = 24 -> 4-bank scatter).
    __shared__ float xs[64][142];         // 36,352 B, single-buffered
    const int b = blockIdx.x;             // 256
    const int cg   = b & 15;
    const int u    = (b >> 4) & 7;
    const int slab = b >> 7;
    const int t = threadIdx.x;
    const int kp = t >> 6;                // ci quarter
    const int lane = t & 63;
    const int coq = lane & 3, vg = lane >> 2;
    const int co = cg*16 + coq*4;
    const int v0 = (vg >> 2) * 2;         // 0,2,4,6
    const int w0 = (vg & 3) * 2;          // 0,2,4,6

    // zero everything once: halo cells stay 0 for the whole kernel
    {
        float* p = &xs[0][0];
        for (int i = t; i < 64*142; i += 256) p[i] = 0.f;
    }

    const float* xbase = J.x + (size_t)slab * HSTRIDE;

    float4 sreg[4];
    auto stage_load = [&](int du) {       // slab uu = u + du - 1 -> registers
        const int uu = u + du - 1;
        const bool ok = (uu >= 0) && (uu < 8);
        const float4* p4 = (const float4*)(xbase + (size_t)uu*64*64);
        #pragma unroll
        for (int p = 0; p < 4; ++p) {
            float4 v = {0.f, 0.f, 0.f, 0.f};
            if (ok) v = p4[p*256 + t];
            sreg[p] = v;
        }
    };
    auto stage_store = [&]() {            // scatter to interior of padded tile
        #pragma unroll
        for (int p = 0; p < 4; ++p) {
            int q = p*256 + t;            // q = vox*16 + ci4
            int vox = q >> 4, ci0 = (q & 15) * 4;
            int idx = ((vox >> 3) + 1)*14 + (vox & 7) + 1;
            xs[ci0+0][idx] = sreg[p].x;
            xs[ci0+1][idx] = sreg[p].y;
            xs[ci0+2][idx] = sreg[p].z;
            xs[ci0+3][idx] = sreg[p].w;
        }
    };

    float4 wv[2][9];
    // weight base is wave-uniform; only coq*16B varies per lane
    auto wload = [&](int du, int ci, int wb) {
        const float* wp = J.wt + (((size_t)(du*576 + ci)) << 8) + cg*16 + coq*4;
        #pragma unroll
        for (int tap = 0; tap < 9; ++tap)
            wv[wb][tap] = *(const float4*)(wp + tap*16384);
    };

    __syncthreads();                      // zero-init complete
    stage_load(0);
    stage_store();
    wload(0, kp*16, 0);
    __syncthreads();                      // du=0 slab staged

    float acc[4][4] = {};
    for (int du = 0; du < 3; ++du) {
        if (du < 2) stage_load(du + 1);   // global -> regs, lands during compute
        #pragma unroll 2
        for (int i = 0; i < 16; ++i) {
            const int kidx = du*16 + i;
            if (kidx < 47)                // 1-ahead weight prefetch
                wload((kidx + 1) >> 4, kp*16 + ((kidx + 1) & 15), (kidx + 1) & 1);
            const int ci = kp*16 + i;
            float xpv[4][4];
            #pragma unroll
            for (int a = 0; a < 4; ++a) {
                const float2* xr = (const float2*)&xs[ci][(v0 + a)*14 + w0];
                float2 lo = xr[0], hi = xr[1];
                xpv[a][0] = lo.x; xpv[a][1] = lo.y;
                xpv[a][2] = hi.x; xpv[a][3] = hi.y;
            }
            const float4* wc = wv[kidx & 1];
            #pragma unroll
            for (int dv = 0; dv < 3; ++dv)
                #pragma unroll
                for (int dw = 0; dw < 3; ++dw) {
                    const float4 wq = wc[dv*3 + dw];
                    #pragma unroll
                    for (int j = 0; j < 4; ++j) {
                        float xv = xpv[(j>>1) + dv][(j&1) + dw];
                        acc[0][j] = fmaf(wq.x, xv, acc[0][j]);
                        acc[1][j] = fmaf(wq.y, xv, acc[1][j]);
                        acc[2][j] = fmaf(wq.z, xv, acc[2][j]);
                        acc[3][j] = fmaf(wq.w, xv, acc[3][j]);
                    }
                }
        }
        __syncthreads();                  // all waves done reading xs[du]
        if (du < 2) {
            stage_store();                // overwrite with du+1 slab
            __syncthreads();
        }
    }

    // K-reduction across the 4 kp classes: reuse xs as red[16][256]
    float* red = &xs[0][0];
    #pragma unroll
    for (int a = 0; a < 4; ++a)
        #pragma unroll
        for (int j = 0; j < 4; ++j)
            red[(a*4 + j)*256 + t] = acc[a][j];
    __syncthreads();
    if (t < 64) {                         // kp==0 class: same (coq,vg) mapping
        const float4 bv = *(const float4*)(J.bias + co);
        float fin[16];
        #pragma unroll
        for (int i = 0; i < 16; ++i)
            fin[i] = red[i*256 + t] + red[i*256 + 64 + t]
                   + red[i*256 + 128 + t] + red[i*256 + 192 + t];
        #pragma unroll
        for (int j = 0; j < 4; ++j) {
            int vox = (v0 + (j>>1))*8 + w0 + (j&1);
            float4 o;
            o.x = fin[0*4+j] + bv.x; o.y = fin[1*4+j] + bv.y;
            o.z = fin[2*4+j] + bv.z; o.w = fin[3*4+j] + bv.w;
            *(float4*)(J.y + (size_t)((slab*512 + u*64 + vox)*256 + co)) = o;
        }
    }
}

// Dual-LN LSTM cell: gates = LN_gin(gi_raw) + LN_gh(ghat or bh), then cx/h
// update. Up to 2 jobs (layer 1 step s, layer 2 step s-1) via blockIdx.y.
__global__ __launch_bounds__(256) void gates_step_kernel(GJob ja, GJob jb)
{
    const GJob J = (blockIdx.y == 0) ? ja : jb;
    const int wid = threadIdx.x >> 6, lane = threadIdx.x & 63;
    const int row = blockIdx.x * 4 + wid;     // nc*512 + vox, < 1024
    const int nc = row >> 9, vox = row & 511;

    const float* g1 = J.giraw + (size_t)row*256;
    float a0 = g1[lane], a1 = g1[64+lane], a2 = g1[128+lane], a3 = g1[192+lane];
    float mu1 = wred_sum(a0+a1+a2+a3) * (1.f/256.f);
    float d0=a0-mu1, d1=a1-mu1, d2=a2-mu1, d3=a3-mu1;
    float v1 = wred_sum(d0*d0+d1*d1+d2*d2+d3*d3) * (1.f/256.f);
    float rs1 = rsqrtf(v1 + 1e-5f);

    const float* g2 = J.k0 ? J.ghat : J.ghat + (size_t)row*256;
    float b0 = g2[lane], b1 = g2[64+lane], b2 = g2[128+lane], b3 = g2[192+lane];
    float mu2 = wred_sum(b0+b1+b2+b3) * (1.f/256.f);
    float e0=b0-mu2, e1=b1-mu2, e2=b2-mu2, e3=b3-mu2;
    float v2 = wred_sum(e0*e0+e1*e1+e2*e2+e3*e3) * (1.f/256.f);
    float rs2 = rsqrtf(v2 + 1e-5f);

    float Ig = d0*rs1*J.ginw[lane]     + J.ginb[lane]     + e0*rs2*J.ghw[lane]     + J.ghb[lane];
    float Fg = d1*rs1*J.ginw[64+lane]  + J.ginb[64+lane]  + e1*rs2*J.ghw[64+lane]  + J.ghb[64+lane];
    float Cg = d2*rs1*J.ginw[128+lane] + J.ginb[128+lane] + e2*rs2*J.ghw[128+lane] + J.ghb[128+lane];
    float Og = d3*rs1*J.ginw[192+lane] + J.ginb[192+lane] + e3*rs2*J.ghw[192+lane] + J.ghb[192+lane];

    float c_old = J.k0 ? 0.f : J.cx[(size_t)row*64 + lane];
    float c_new = fsig(Fg)*c_old + fsig(Ig)*ftanh(Cg);
    float h_new = fsig(Og)*ftanh(c_new);
    J.cx[(size_t)row*64 + lane] = c_new;
    J.h[((size_t)(nc*7 + J.k)*512 + vox)*64 + lane] = h_new;
}

// Head: 4 voxels per block, one wave per voxel (reads layer-2 h).
__global__ __launch_bounds__(256) void head_kernel(
    const float* __restrict__ h,      // [2][7][512][64]
    const float* __restrict__ w1, const float* __restrict__ b1,
    const float* __restrict__ lng, const float* __restrict__ lnb,
    const float* __restrict__ w2, const float* __restrict__ b2,
    const int* __restrict__ ncode,
    float* __restrict__ out)
{
    __shared__ float zv[4][64];
    __shared__ float lg[4][512];
    const int blk = blockIdx.x;               // 768 = 2n * 3sn * 128 voxgroups
    const int n = blk / 384;
    const int sn = (blk / 128) % 3;
    const int vox0 = (blk & 127) * 4;
    const int wid = threadIdx.x >> 6, lane = threadIdx.x & 63;
    const int vox = vox0 + wid;
    const int r = (n*3 + sn)*512 + vox;       // pred row
    const float* hv = h + (size_t)((n*7 + sn + 4)*512 + vox)*64;

    float yv = b1[lane];
    for (int kk = 0; kk < 64; ++kk) yv = fmaf(hv[kk], w1[kk*64 + lane], yv);
    float mu = wred_sum(yv) * (1.f/64.f);
    float d = yv - mu;
    float var = wred_sum(d*d) * (1.f/64.f);
    float ln = d * rsqrtf(var + 1e-5f) * lng[lane] + lnb[lane];
    zv[wid][lane] = 0.5f * ln * (1.f + erff(ln * 0.70710678118654752f));

    float l[8];
    #pragma unroll
    for (int j = 0; j < 8; ++j) l[j] = b2[j*64 + lane];
    for (int kk = 0; kk < 64; ++kk) {
        float zz = zv[wid][kk];
        #pragma unroll
        for (int j = 0; j < 8; ++j)
            l[j] = fmaf(zz, w2[kk*512 + j*64 + lane], l[j]);
    }
    #pragma unroll
    for (int j = 0; j < 8; ++j) lg[wid][j*64 + lane] = l[j];

    float m = l[0]; int mi = lane;
    #pragma unroll
    for (int j = 1; j < 8; ++j)
        if (l[j] > m) { m = l[j]; mi = j*64 + lane; }
    #pragma unroll
    for (int o = 32; o > 0; o >>= 1) {
        float om = __shfl_down(m, o, 64);
        int   oi = __shfl_down(mi, o, 64);
        if (om > m || (om == m && oi < mi)) { m = om; mi = oi; }
    }
    float maxv = __shfl(m, 0, 64);
    int   maxi = __shfl(mi, 0, 64);
    float es = 0.f;
    #pragma unroll
    for (int j = 0; j < 8; ++j) es += __expf(l[j] - maxv);
    float sum = wred_sum(es);
    if (lane == 0) {
        int target = ncode[(n*3 + sn)*512 + vox];
        float logp = lg[wid][target] - maxv - __logf(sum);
        atomicAdd(out + 1572864, -logp * (1.f/3072.f));
        out[1572865 + r] = (float)maxi;
    }

    __syncthreads();
    const int t = threadIdx.x;
    #pragma unroll
    for (int jj = 0; jj < 2; ++jj) {
        int co = t + jj*256;
        float4 o4 = { lg[0][co], lg[1][co], lg[2][co], lg[3][co] };
        *(float4*)(out + (size_t)((n*512 + co)*3 + sn)*512 + vox0) = o4;
    }
}

extern "C" void kernel_launch(void* const* d_in, const int* in_sizes, int n_in,
                              void* d_out, int out_size, void* d_ws, size_t ws_size,
                              hipStream_t stream) {
    (void)in_sizes; (void)n_in; (void)out_size; (void)ws_size;
    const int*   code  = (const int*)d_in[0];
    const int*   ncode = (const int*)d_in[1];
    const float* emb   = (const float*)d_in[2];
    const float* win   = (const float*)d_in[3];
    const float* bin_  = (const float*)d_in[4];
    const float* gin_w = (const float*)d_in[5];
    const float* gin_b = (const float*)d_in[6];
    const float* wh    = (const float*)d_in[7];
    const float* bh    = (const float*)d_in[8];
    const float* gh_w  = (const float*)d_in[9];
    const float* gh_b  = (const float*)d_in[10];
    const float* w1    = (const float*)d_in[11];
    const float* b1    = (const float*)d_in[12];
    const float* ln_g  = (const float*)d_in[13];
    const float* ln_b  = (const float*)d_in[14];
    const float* w2    = (const float*)d_in[15];
    const float* b2    = (const float*)d_in[16];
    float* out = (float*)d_out;

    float* h1     = (float*)d_ws;          // [2][7][512][64] (emb -> h1)
    float* h2     = h1 + 458752;           // [2][7][512][64]
    float* gi1raw = h2 + 458752;           // [2][512][256]
    float* gi2raw = gi1raw + 262144;       // [2][512][256]
    float* ghat1  = gi2raw + 262144;       // [2][512][256]
    float* ghat2  = ghat1 + 262144;        // [2][512][256]
    float* cx1    = ghat2 + 262144;        // [2][512][64]
    float* cx2    = cx1 + 65536;           // [2][512][64]

    hipMemsetAsync(out + 1572864, 0, sizeof(float), stream);   // loss accumulator
    embed_kernel<<<1792, 256, 0, stream>>>(code, ncode, emb, h1);

    // pre-loop: gi1raw(0) = conv(emb h1[0]) + bin1
    {
        CJob j = { h1 + 0*XS, win, bin_, gi1raw };
        conv_step_kernel<<<dim3(256, 1), 256, 0, stream>>>(j, j, j, j);
    }

    for (int s = 0; s <= 7; ++s) {
        // ---- gates launch: gates1(s) [s<=6], gates2(s-1) [s>=1] ----
        GJob g1 = { gi1raw, (s == 0) ? bh : ghat1,
                    gin_w, gin_b, gh_w, gh_b, cx1, h1, s, s == 0 };
        GJob g2 = { gi2raw, (s == 1) ? bh + 256 : ghat2,
                    gin_w + 256, gin_b + 256, gh_w + 256, gh_b + 256,
                    cx2, h2, s - 1, s == 1 };
        if (s == 0)
            gates_step_kernel<<<dim3(256, 1), 256, 0, stream>>>(g1, g1);
        else if (s <= 6)
            gates_step_kernel<<<dim3(256, 2), 256, 0, stream>>>(g1, g2);
        else
            gates_step_kernel<<<dim3(256, 1), 256, 0, stream>>>(g2, g2);

        // ---- conv launch: in1(s+1), rec1(s), in2(s), rec2(s) ----
        CJob jobs[4]; int nj = 0;
        if (s <= 5) jobs[nj++] = { h1 + (s+1)*XS, win, bin_, gi1raw };               // in1(s+1)
        if (s <= 5) jobs[nj++] = { h1 + s*XS, wh, bh, ghat1 };                        // rec1(s)
        if (s <= 6) jobs[nj++] = { h1 + s*XS, win + WSTRIDE, bin_ + 256, gi2raw };    // in2(s)
        if (s >= 1 && s <= 6)
                    jobs[nj++] = { h2 + (s-1)*XS, wh + WSTRIDE, bh + 256, ghat2 };    // rec2(s)
        if (nj > 0)
            conv_step_kernel<<<dim3(256, nj), 256, 0, stream>>>(
                jobs[0], jobs[nj > 1 ? 1 : 0], jobs[nj > 2 ? 2 : 0], jobs[nj > 3 ? 3 : 0]);
    }

    head_kernel<<<768, 256, 0, stream>>>(h2, w1, b1, ln_g, ln_b, w2, b2, ncode, out);
}

// Round 14
// 612.298 us; speedup vs baseline: 4.7992x; 4.7992x over previous
//
#include <hip/hip_runtime.h>

// ConvLSTM fp32, round 14: r10 inner loop verbatim (VGPR 108, no spill) +
// single-buffered flat xs[64][142] (36.4KB -> 4 blocks/CU via LDS) +
// __launch_bounds__(256,2) kept from r10 (r13's (256,4) capped VGPR at 128
// and spilled catastrophically). Stride 142: staging scatter 8-way -> 4-way.

#define WSTRIDE 442368   // per-layer conv weight elements: 27*64*256
#define XS      32768    // one k-slab of h: 512*64
#define HSTRIDE 229376   // nc stride of h: 7*512*64

__device__ __forceinline__ float wred_sum(float v) {
    #pragma unroll
    for (int o = 32; o > 0; o >>= 1) v += __shfl_down(v, o, 64);
    return __shfl(v, 0, 64);
}
__device__ __forceinline__ float fsig(float x)  { return 1.f / (1.f + __expf(-x)); }
__device__ __forceinline__ float ftanh(float x) { return 1.f - 2.f / (__expf(2.f*x) + 1.f); }

struct CJob { const float* x; const float* wt; const float* bias; float* y; };
struct GJob {
    const float* giraw; const float* ghat;
    const float* ginw; const float* ginb;
    const float* ghw;  const float* ghb;
    float* cx; float* h; int k; int k0;
};

// h[nc][s][vox][ch] = emb[tok][ch]
__global__ __launch_bounds__(256) void embed_kernel(
    const int* __restrict__ code, const int* __restrict__ ncode,
    const float* __restrict__ emb, float* __restrict__ h)
{
    int e = blockIdx.x * 256 + threadIdx.x;   // < 2*7*512*64 = 458752
    int ch = e & 63;
    int pos = e >> 6;            // nc*7*512 + s*512 + vox
    int vox = pos & 511;
    int t = pos >> 9;            // nc*7 + s
    int s = t % 7, nc = t / 7;
    int tok = (s < 5) ? code[(nc*5 + s)*512 + vox]
                      : ncode[(nc*3 + (s-5))*512 + vox];
    h[e] = emb[tok*64 + ch];
}

// One 3x3x3 SAME conv job (Cin=64 -> Cout=256) over 2 slabs; up to 4 jobs
// per launch via blockIdx.y. Block = full u-plane (64 vox) x 16 co,
// thread = 4co x 4vox (2x2 patch), K(ci) split 4-way + LDS reduce.
// grid.x per job = 2 slab * 8 u * 16 cg = 256.
__global__ __launch_bounds__(256, 2) void conv_step_kernel(CJob j0, CJob j1, CJob j2, CJob j3)
{
    CJob J = j0;
    if (blockIdx.y == 1) J = j1;
    else if (blockIdx.y == 2) J = j2;
    else if (blockIdx.y == 3) J = j3;

    // flat halo-padded du-slab tile: row stride 14 (10 rows used), ci stride
    // 142 (even -> b64-aligned reads; 4*142 % 32 = 24 -> 4-bank scatter).
    __shared__ float xs[64][142];         // 36,352 B, single-buffered
    const int b = blockIdx.x;             // 256
    const int cg   = b & 15;
    const int u    = (b >> 4) & 7;
    const int slab = b >> 7;
    const int t = threadIdx.x;
    const int kp = t >> 6;                // ci quarter (wave-uniform)
    const int lane = t & 63;
    const int coq = lane & 3, vg = lane >> 2;
    const int co = cg*16 + coq*4;
    const int v0 = (vg >> 2) * 2;         // 0,2,4,6
    const int w0 = (vg & 3) * 2;          // 0,2,4,6

    // zero everything once: halo cells stay 0 for the whole kernel
    {
        float* p = &xs[0][0];
        for (int i = t; i < 64*142; i += 256) p[i] = 0.f;
    }

    const float* xbase = J.x + (size_t)slab * HSTRIDE;

    float4 sreg[4];
    auto stage_load = [&](int du) {       // slab uu = u + du - 1 -> registers
        const int uu = u + du - 1;
        const bool ok = (uu >= 0) && (uu < 8);
        const float4* p4 = (const float4*)(xbase + (size_t)uu*64*64);
        #pragma unroll
        for (int p = 0; p < 4; ++p) {
            float4 v = {0.f, 0.f, 0.f, 0.f};
            if (ok) v = p4[p*256 + t];
            sreg[p] = v;
        }
    };
    auto stage_store = [&]() {            // scatter to interior of padded tile
        #pragma unroll
        for (int p = 0; p < 4; ++p) {
            int q = p*256 + t;            // q = vox*16 + ci4
            int vox = q >> 4, ci0 = (q & 15) * 4;
            int idx = ((vox >> 3) + 1)*14 + (vox & 7) + 1;
            xs[ci0+0][idx] = sreg[p].x;
            xs[ci0+1][idx] = sreg[p].y;
            xs[ci0+2][idx] = sreg[p].z;
            xs[ci0+3][idx] = sreg[p].w;
        }
    };

    float4 wv[2][9];
    // weight base is wave-uniform; only coq*16B varies per lane
    auto wload = [&](int du, int ci, int wb) {
        const float* wp = J.wt + (((size_t)(du*576 + ci)) << 8) + cg*16 + coq*4;
        #pragma unroll
        for (int tap = 0; tap < 9; ++tap)
            wv[wb][tap] = *(const float4*)(wp + tap*16384);
    };

    __syncthreads();                      // zero-init complete
    stage_load(0);
    stage_store();
    wload(0, kp*16, 0);
    __syncthreads();                      // du=0 slab staged

    float acc[4][4] = {};
    for (int du = 0; du < 3; ++du) {
        if (du < 2) stage_load(du + 1);   // global -> regs, lands during compute
        #pragma unroll 2
        for (int i = 0; i < 16; ++i) {
            const int kidx = du*16 + i;
            if (kidx < 47)                // 1-ahead weight prefetch
                wload((kidx + 1) >> 4, kp*16 + ((kidx + 1) & 15), (kidx + 1) & 1);
            const int ci = kp*16 + i;
            float xpv[4][4];
            #pragma unroll
            for (int a = 0; a < 4; ++a) {
                const float2* xr = (const float2*)&xs[ci][(v0 + a)*14 + w0];
                float2 lo = xr[0], hi = xr[1];
                xpv[a][0] = lo.x; xpv[a][1] = lo.y;
                xpv[a][2] = hi.x; xpv[a][3] = hi.y;
            }
            const float4* wc = wv[kidx & 1];
            #pragma unroll
            for (int dv = 0; dv < 3; ++dv)
                #pragma unroll
                for (int dw = 0; dw < 3; ++dw) {
                    const float4 wq = wc[dv*3 + dw];
                    #pragma unroll
                    for (int j = 0; j < 4; ++j) {
                        float xv = xpv[(j>>1) + dv][(j&1) + dw];
                        acc[0][j] = fmaf(wq.x, xv, acc[0][j]);
                        acc[1][j] = fmaf(wq.y, xv, acc[1][j]);
                        acc[2][j] = fmaf(wq.z, xv, acc[2][j]);
                        acc[3][j] = fmaf(wq.w, xv, acc[3][j]);
                    }
                }
        }
        __syncthreads();                  // all waves done reading xs[du]
        if (du < 2) {
            stage_store();                // overwrite with du+1 slab
            __syncthreads();
        }
    }

    // K-reduction across the 4 kp classes: reuse xs as red[16][256]
    float* red = &xs[0][0];
    #pragma unroll
    for (int a = 0; a < 4; ++a)
        #pragma unroll
        for (int j = 0; j < 4; ++j)
            red[(a*4 + j)*256 + t] = acc[a][j];
    __syncthreads();
    if (t < 64) {                         // kp==0 class: same (coq,vg) mapping
        const float4 bv = *(const float4*)(J.bias + co);
        float fin[16];
        #pragma unroll
        for (int i = 0; i < 16; ++i)
            fin[i] = red[i*256 + t] + red[i*256 + 64 + t]
                   + red[i*256 + 128 + t] + red[i*256 + 192 + t];
        #pragma unroll
        for (int j = 0; j < 4; ++j) {
            int vox = (v0 + (j>>1))*8 + w0 + (j&1);
            float4 o;
            o.x = fin[0*4+j] + bv.x; o.y = fin[1*4+j] + bv.y;
            o.z = fin[2*4+j] + bv.z; o.w = fin[3*4+j] + bv.w;
            *(float4*)(J.y + (size_t)((slab*512 + u*64 + vox)*256 + co)) = o;
        }
    }
}

// Dual-LN LSTM cell: gates = LN_gin(gi_raw) + LN_gh(ghat or bh), then cx/h
// update. Up to 2 jobs (layer 1 step s, layer 2 step s-1) via blockIdx.y.
__global__ __launch_bounds__(256) void gates_step_kernel(GJob ja, GJob jb)
{
    const GJob J = (blockIdx.y == 0) ? ja : jb;
    const int wid = threadIdx.x >> 6, lane = threadIdx.x & 63;
    const int row = blockIdx.x * 4 + wid;     // nc*512 + vox, < 1024
    const int nc = row >> 9, vox = row & 511;

    const float* g1 = J.giraw + (size_t)row*256;
    float a0 = g1[lane], a1 = g1[64+lane], a2 = g1[128+lane], a3 = g1[192+lane];
    float mu1 = wred_sum(a0+a1+a2+a3) * (1.f/256.f);
    float d0=a0-mu1, d1=a1-mu1, d2=a2-mu1, d3=a3-mu1;
    float v1 = wred_sum(d0*d0+d1*d1+d2*d2+d3*d3) * (1.f/256.f);
    float rs1 = rsqrtf(v1 + 1e-5f);

    const float* g2 = J.k0 ? J.ghat : J.ghat + (size_t)row*256;
    float b0 = g2[lane], b1 = g2[64+lane], b2 = g2[128+lane], b3 = g2[192+lane];
    float mu2 = wred_sum(b0+b1+b2+b3) * (1.f/256.f);
    float e0=b0-mu2, e1=b1-mu2, e2=b2-mu2, e3=b3-mu2;
    float v2 = wred_sum(e0*e0+e1*e1+e2*e2+e3*e3) * (1.f/256.f);
    float rs2 = rsqrtf(v2 + 1e-5f);

    float Ig = d0*rs1*J.ginw[lane]     + J.ginb[lane]     + e0*rs2*J.ghw[lane]     + J.ghb[lane];
    float Fg = d1*rs1*J.ginw[64+lane]  + J.ginb[64+lane]  + e1*rs2*J.ghw[64+lane]  + J.ghb[64+lane];
    float Cg = d2*rs1*J.ginw[128+lane] + J.ginb[128+lane] + e2*rs2*J.ghw[128+lane] + J.ghb[128+lane];
    float Og = d3*rs1*J.ginw[192+lane] + J.ginb[192+lane] + e3*rs2*J.ghw[192+lane] + J.ghb[192+lane];

    float c_old = J.k0 ? 0.f : J.cx[(size_t)row*64 + lane];
    float c_new = fsig(Fg)*c_old + fsig(Ig)*ftanh(Cg);
    float h_new = fsig(Og)*ftanh(c_new);
    J.cx[(size_t)row*64 + lane] = c_new;
    J.h[((size_t)(nc*7 + J.k)*512 + vox)*64 + lane] = h_new;
}

// Head: 4 voxels per block, one wave per voxel (reads layer-2 h).
__global__ __launch_bounds__(256) void head_kernel(
    const float* __restrict__ h,      // [2][7][512][64]
    const float* __restrict__ w1, const float* __restrict__ b1,
    const float* __restrict__ lng, const float* __restrict__ lnb,
    const float* __restrict__ w2, const float* __restrict__ b2,
    const int* __restrict__ ncode,
    float* __restrict__ out)
{
    __shared__ float zv[4][64];
    __shared__ float lg[4][512];
    const int blk = blockIdx.x;               // 768 = 2n * 3sn * 128 voxgroups
    const int n = blk / 384;
    const int sn = (blk / 128) % 3;
    const int vox0 = (blk & 127) * 4;
    const int wid = threadIdx.x >> 6, lane = threadIdx.x & 63;
    const int vox = vox0 + wid;
    const int r = (n*3 + sn)*512 + vox;       // pred row
    const float* hv = h + (size_t)((n*7 + sn + 4)*512 + vox)*64;

    float yv = b1[lane];
    for (int kk = 0; kk < 64; ++kk) yv = fmaf(hv[kk], w1[kk*64 + lane], yv);
    float mu = wred_sum(yv) * (1.f/64.f);
    float d = yv - mu;
    float var = wred_sum(d*d) * (1.f/64.f);
    float ln = d * rsqrtf(var + 1e-5f) * lng[lane] + lnb[lane];
    zv[wid][lane] = 0.5f * ln * (1.f + erff(ln * 0.70710678118654752f));

    float l[8];
    #pragma unroll
    for (int j = 0; j < 8; ++j) l[j] = b2[j*64 + lane];
    for (int kk = 0; kk < 64; ++kk) {
        float zz = zv[wid][kk];
        #pragma unroll
        for (int j = 0; j < 8; ++j)
            l[j] = fmaf(zz, w2[kk*512 + j*64 + lane], l[j]);
    }
    #pragma unroll
    for (int j = 0; j < 8; ++j) lg[wid][j*64 + lane] = l[j];

    float m = l[0]; int mi = lane;
    #pragma unroll
    for (int j = 1; j < 8; ++j)
        if (l[j] > m) { m = l[j]; mi = j*64 + lane; }
    #pragma unroll
    for (int o = 32; o > 0; o >>= 1) {
        float om = __shfl_down(m, o, 64);
        int   oi = __shfl_down(mi, o, 64);
        if (om > m || (om == m && oi < mi)) { m = om; mi = oi; }
    }
    float maxv = __shfl(m, 0, 64);
    int   maxi = __shfl(mi, 0, 64);
    float es = 0.f;
    #pragma unroll
    for (int j = 0; j < 8; ++j) es += __expf(l[j] - maxv);
    float sum = wred_sum(es);
    if (lane == 0) {
        int target = ncode[(n*3 + sn)*512 + vox];
        float logp = lg[wid][target] - maxv - __logf(sum);
        atomicAdd(out + 1572864, -logp * (1.f/3072.f));
        out[1572865 + r] = (float)maxi;
    }

    __syncthreads();
    const int t = threadIdx.x;
    #pragma unroll
    for (int jj = 0; jj < 2; ++jj) {
        int co = t + jj*256;
        float4 o4 = { lg[0][co], lg[1][co], lg[2][co], lg[3][co] };
        *(float4*)(out + (size_t)((n*512 + co)*3 + sn)*512 + vox0) = o4;
    }
}

extern "C" void kernel_launch(void* const* d_in, const int* in_sizes, int n_in,
                              void* d_out, int out_size, void* d_ws, size_t ws_size,
                              hipStream_t stream) {
    (void)in_sizes; (void)n_in; (void)out_size; (void)ws_size;
    const int*   code  = (const int*)d_in[0];
    const int*   ncode = (const int*)d_in[1];
    const float* emb   = (const float*)d_in[2];
    const float* win   = (const float*)d_in[3];
    const float* bin_  = (const float*)d_in[4];
    const float* gin_w = (const float*)d_in[5];
    const float* gin_b = (const float*)d_in[6];
    const float* wh    = (const float*)d_in[7];
    const float* bh    = (const float*)d_in[8];
    const float* gh_w  = (const float*)d_in[9];
    const float* gh_b  = (const float*)d_in[10];
    const float* w1    = (const float*)d_in[11];
    const float* b1    = (const float*)d_in[12];
    const float* ln_g  = (const float*)d_in[13];
    const float* ln_b  = (const float*)d_in[14];
    const float* w2    = (const float*)d_in[15];
    const float* b2    = (const float*)d_in[16];
    float* out = (float*)d_out;

    float* h1     = (float*)d_ws;          // [2][7][512][64] (emb -> h1)
    float* h2     = h1 + 458752;           // [2][7][512][64]
    float* gi1raw = h2 + 458752;           // [2][512][256]
    float* gi2raw = gi1raw + 262144;       // [2][512][256]
    float* ghat1  = gi2raw + 262144;       // [2][512][256]
    float* ghat2  = ghat1 + 262144;        // [2][512][256]
    float* cx1    = ghat2 + 262144;        // [2][512][64]
    float* cx2    = cx1 + 65536;           // [2][512][64]

    hipMemsetAsync(out + 1572864, 0, sizeof(float), stream);   // loss accumulator
    embed_kernel<<<1792, 256, 0, stream>>>(code, ncode, emb, h1);

    // pre-loop: gi1raw(0) = conv(emb h1[0]) + bin1
    {
        CJob j = { h1 + 0*XS, win, bin_, gi1raw };
        conv_step_kernel<<<dim3(256, 1), 256, 0, stream>>>(j, j, j, j);
    }

    for (int s = 0; s <= 7; ++s) {
        // ---- gates launch: gates1(s) [s<=6], gates2(s-1) [s>=1] ----
        GJob g1 = { gi1raw, (s == 0) ? bh : ghat1,
                    gin_w, gin_b, gh_w, gh_b, cx1, h1, s, s == 0 };
        GJob g2 = { gi2raw, (s == 1) ? bh + 256 : ghat2,
                    gin_w + 256, gin_b + 256, gh_w + 256, gh_b + 256,
                    cx2, h2, s - 1, s == 1 };
        if (s == 0)
            gates_step_kernel<<<dim3(256, 1), 256, 0, stream>>>(g1, g1);
        else if (s <= 6)
            gates_step_kernel<<<dim3(256, 2), 256, 0, stream>>>(g1, g2);
        else
            gates_step_kernel<<<dim3(256, 1), 256, 0, stream>>>(g2, g2);

        // ---- conv launch: in1(s+1), rec1(s), in2(s), rec2(s) ----
        CJob jobs[4]; int nj = 0;
        if (s <= 5) jobs[nj++] = { h1 + (s+1)*XS, win, bin_, gi1raw };               // in1(s+1)
        if (s <= 5) jobs[nj++] = { h1 + s*XS, wh, bh, ghat1 };                        // rec1(s)
        if (s <= 6) jobs[nj++] = { h1 + s*XS, win + WSTRIDE, bin_ + 256, gi2raw };    // in2(s)
        if (s >= 1 && s <= 6)
                    jobs[nj++] = { h2 + (s-1)*XS, wh + WSTRIDE, bh + 256, ghat2 };    // rec2(s)
        if (nj > 0)
            conv_step_kernel<<<dim3(256, nj), 256, 0, stream>>>(
                jobs[0], jobs[nj > 1 ? 1 : 0], jobs[nj > 2 ? 2 : 0], jobs[nj > 3 ? 3 : 0]);
    }

    head_kernel<<<768, 256, 0, stream>>>(h2, w1, b1, ln_g, ln_b, w2, b2, ncode, out);
}